// Round 4
// baseline (5748.129 us; speedup 1.0000x reference)
//
#include <hip/hip_runtime.h>

// GIN forward, MI355X. Round 4:
//  - GEMMs restructured: 64-row tile per 256-thread block, 4 waves each owning a
//    16-column slice. Grid 391 -> 1563 blocks (6 -> 24 waves/CU), acc[64] -> acc[16]
//    (old kernel spilled: VGPR_Count=44 < 64 accumulators). Wave-level W reuse via
//    scalar loads, A-tile reuse via L1.
//  - Column stats (sum/sumsq) fused into GEMM epilogues via 64-lane butterfly reduce
//    + 1 atomic per column per block. All 8 standalone k_colstats passes removed.
//  - Final 64x10 GEMM: K-split across 4 waves + LDS reduce.
//  - CSR build: bucketed partition + LDS-local scatter (Round 3).
//  - k_agg: hierarchical unroll (8/4/2/1).

#define HID 64
#define LAYERS 3
#define BN_EPS 1e-5f

#define BK_SHIFT 8          // 256 nodes per bucket
#define BK_MAX 512          // max buckets supported (N <= 131072)
#define PART_EPT 16         // edges per thread in k_bpart

__device__ __forceinline__ float relu_aff(float x, float s, float t) {
    return fmaxf(fmaf(x, s, t), 0.f);
}

// compute affine (s,t) for column c from raw sums
__device__ __forceinline__ void bn_fin(const float* __restrict__ raw, const float* __restrict__ g,
                                       const float* __restrict__ b, float invN, int c,
                                       float& s, float& t) {
    float m = raw[c] * invN;
    float v = fmaf(-m, m, raw[64 + c] * invN);
    float r = rsqrtf(v + BN_EPS);
    s = r * g[c];
    t = fmaf(-m, s, b[c]);
}

// ---------------- bucketed CSR build ----------------

__global__ __launch_bounds__(256) void k_bhist(const int* __restrict__ dst, int* __restrict__ gh,
                                               int E, int nbk) {
    __shared__ int h[BK_MAX];
    for (int i = threadIdx.x; i < BK_MAX; i += 256) h[i] = 0;
    __syncthreads();
    int stride = gridDim.x * 256;
    for (int e = blockIdx.x * 256 + threadIdx.x; e < E; e += stride)
        atomicAdd(&h[dst[e] >> BK_SHIFT], 1);
    __syncthreads();
    for (int i = threadIdx.x; i < nbk; i += 256)
        if (h[i]) atomicAdd(&gh[i], h[i]);
}

__global__ __launch_bounds__(512) void k_bscan(const int* __restrict__ gh, int* __restrict__ boff,
                                               int* __restrict__ gcur, int nbk) {
    int lane = threadIdx.x & 63, wid = threadIdx.x >> 6;
    int v = (threadIdx.x < nbk) ? gh[threadIdx.x] : 0;
    int incl = v;
    for (int d = 1; d < 64; d <<= 1) { int y = __shfl_up(incl, d); if (lane >= d) incl += y; }
    __shared__ int ws[8];
    if (lane == 63) ws[wid] = incl;
    __syncthreads();
    if (threadIdx.x == 0) { int a = 0; for (int w = 0; w < 8; w++) { int t = ws[w]; ws[w] = a; a += t; } }
    __syncthreads();
    int excl = incl - v + ws[wid];
    if (threadIdx.x < nbk) { boff[threadIdx.x] = excl; gcur[threadIdx.x] = excl; }
    if (threadIdx.x == nbk - 1) boff[nbk] = excl + v;
}

__global__ __launch_bounds__(256) void k_bpart(const int* __restrict__ src, const int* __restrict__ dst,
                                               int* __restrict__ gcur, unsigned* __restrict__ pairs,
                                               int E) {
    __shared__ int h[BK_MAX], cur[BK_MAX], base[BK_MAX];
    int e0 = blockIdx.x * (256 * PART_EPT);
    int eend = min(e0 + 256 * PART_EPT, E);
    for (int i = threadIdx.x; i < BK_MAX; i += 256) h[i] = 0;
    __syncthreads();
    for (int e = e0 + threadIdx.x; e < eend; e += 256)
        atomicAdd(&h[dst[e] >> BK_SHIFT], 1);
    __syncthreads();
    for (int i = threadIdx.x; i < BK_MAX; i += 256) {
        cur[i] = 0;
        base[i] = h[i] ? atomicAdd(&gcur[i], h[i]) : 0;
    }
    __syncthreads();
    for (int e = e0 + threadIdx.x; e < eend; e += 256) {
        int d = dst[e];
        int b = d >> BK_SHIFT;
        int r = atomicAdd(&cur[b], 1);
        pairs[base[b] + r] = ((unsigned)(d & ((1 << BK_SHIFT) - 1)) << 24) | (unsigned)src[e];
    }
}

__global__ __launch_bounds__(256) void k_bucket_csr(const unsigned* __restrict__ pairs,
                                                    const int* __restrict__ boff,
                                                    int* __restrict__ row_off, int* __restrict__ col,
                                                    int N, int E, int nbk) {
    int b = blockIdx.x;
    int p0 = boff[b], p1 = boff[b + 1];
    int base_node = b << BK_SHIFT;
    int nn = min(256, N - base_node);
    __shared__ int h[256], cur[256];
    h[threadIdx.x] = 0;
    __syncthreads();
    for (int p = p0 + threadIdx.x; p < p1; p += 256)
        atomicAdd(&h[pairs[p] >> 24], 1);
    __syncthreads();
    int v = h[threadIdx.x];
    int lane = threadIdx.x & 63, wid = threadIdx.x >> 6;
    int incl = v;
    for (int d = 1; d < 64; d <<= 1) { int y = __shfl_up(incl, d); if (lane >= d) incl += y; }
    __shared__ int ws[4];
    if (lane == 63) ws[wid] = incl;
    __syncthreads();
    if (threadIdx.x == 0) { int a = 0; for (int w = 0; w < 4; w++) { int t = ws[w]; ws[w] = a; a += t; } }
    __syncthreads();
    int excl = incl - v + ws[wid];
    if (threadIdx.x < nn) row_off[base_node + threadIdx.x] = p0 + excl;
    if (b == nbk - 1 && threadIdx.x == 0) row_off[N] = E;
    cur[threadIdx.x] = excl;
    __syncthreads();
    for (int p = p0 + threadIdx.x; p < p1; p += 256) {
        unsigned pk = pairs[p];
        int local = pk >> 24;
        int r = atomicAdd(&cur[local], 1);
        col[p0 + r] = (int)(pk & 0xFFFFFFu);
    }
}

// ---------------- aggregation: o = (1+eps)*act(h) + sum act(h[src]) ----------------
__global__ __launch_bounds__(256) void k_agg(const float* __restrict__ hb,
                                             const float* __restrict__ raw, const float* __restrict__ g,
                                             const float* __restrict__ b, float invN,
                                             const int* __restrict__ row_off, const int* __restrict__ col,
                                             const float* __restrict__ epsp, int li,
                                             float* __restrict__ o, int n) {
    int wid = threadIdx.x >> 6, lane = threadIdx.x & 63;
    int node = blockIdx.x * 4 + wid;
    if (node >= n) return;
    float s, t;
    bn_fin(raw, g, b, invN, lane, s, t);
    float ope = 1.f + epsp[li];
    float acc = ope * relu_aff(hb[(size_t)node * HID + lane], s, t);
    int e = row_off[node], b1 = row_off[node + 1];

    while (e + 8 <= b1) {
        int i0 = col[e], i1 = col[e + 1], i2 = col[e + 2], i3 = col[e + 3];
        int i4 = col[e + 4], i5 = col[e + 5], i6 = col[e + 6], i7 = col[e + 7];
        float v0 = hb[(size_t)i0 * HID + lane], v1 = hb[(size_t)i1 * HID + lane];
        float v2 = hb[(size_t)i2 * HID + lane], v3 = hb[(size_t)i3 * HID + lane];
        float v4 = hb[(size_t)i4 * HID + lane], v5 = hb[(size_t)i5 * HID + lane];
        float v6 = hb[(size_t)i6 * HID + lane], v7 = hb[(size_t)i7 * HID + lane];
        acc += relu_aff(v0, s, t) + relu_aff(v1, s, t) + relu_aff(v2, s, t) + relu_aff(v3, s, t);
        acc += relu_aff(v4, s, t) + relu_aff(v5, s, t) + relu_aff(v6, s, t) + relu_aff(v7, s, t);
        e += 8;
    }
    if (e + 4 <= b1) {
        int i0 = col[e], i1 = col[e + 1], i2 = col[e + 2], i3 = col[e + 3];
        float v0 = hb[(size_t)i0 * HID + lane], v1 = hb[(size_t)i1 * HID + lane];
        float v2 = hb[(size_t)i2 * HID + lane], v3 = hb[(size_t)i3 * HID + lane];
        acc += relu_aff(v0, s, t) + relu_aff(v1, s, t) + relu_aff(v2, s, t) + relu_aff(v3, s, t);
        e += 4;
    }
    if (e + 2 <= b1) {
        int i0 = col[e], i1 = col[e + 1];
        float v0 = hb[(size_t)i0 * HID + lane], v1 = hb[(size_t)i1 * HID + lane];
        acc += relu_aff(v0, s, t) + relu_aff(v1, s, t);
        e += 2;
    }
    if (e < b1) acc += relu_aff(hb[(size_t)col[e] * HID + lane], s, t);

    o[(size_t)node * HID + lane] = acc;
}

// ---------------- tiled GEMM: C[n x 64] = act(A[n x 64]) @ W[64 x 64] + bias ----------------
// block = 256 threads = 4 waves over a 64-row tile; wave w owns cols [16w, 16w+16).
// AFF: act = relu_aff with (s,t) from LDS prologue. STATS: fused column sum/sumsq of C
// via 64-lane butterfly + 1 atomic per col per block.
template <bool AFF, bool STATS>
__global__ __launch_bounds__(256) void k_gemm_t64(const float* __restrict__ A,
                                                  const float* __restrict__ raw, const float* __restrict__ g,
                                                  const float* __restrict__ b, float invN,
                                                  const float* __restrict__ W, const float* __restrict__ bias,
                                                  float* __restrict__ C, float* __restrict__ rawOut, int n) {
    __shared__ float stl[2 * HID];
    if (AFF) {
        if (threadIdx.x < HID) {
            float s, t;
            bn_fin(raw, g, b, invN, threadIdx.x, s, t);
            stl[threadIdx.x] = s;
            stl[HID + threadIdx.x] = t;
        }
        __syncthreads();
    }
    int w = threadIdx.x >> 6, lane = threadIdx.x & 63;
    int row = blockIdx.x * 64 + lane;
    int c0 = w * 16;
    bool valid = row < n;
    float acc[16];
#pragma unroll
    for (int j = 0; j < 16; j++) acc[j] = valid ? bias[c0 + j] : 0.f;
    if (valid) {
        const float4* a4 = (const float4*)(A + (size_t)row * HID);
#pragma unroll 4
        for (int kk = 0; kk < HID / 4; kk++) {
            float4 av = a4[kk];
            float a[4] = {av.x, av.y, av.z, av.w};
#pragma unroll
            for (int u = 0; u < 4; u++) {
                int k = kk * 4 + u;
                float xv = a[u];
                if (AFF) xv = relu_aff(xv, stl[k], stl[HID + k]);
#pragma unroll
                for (int j = 0; j < 16; j++) acc[j] = fmaf(xv, W[k * HID + c0 + j], acc[j]);
            }
        }
        float4* cp = (float4*)(C + (size_t)row * HID + c0);
#pragma unroll
        for (int j = 0; j < 4; j++)
            cp[j] = make_float4(acc[4 * j], acc[4 * j + 1], acc[4 * j + 2], acc[4 * j + 3]);
    }
    if (STATS) {
        // invalid lanes contribute acc==0; no early returns above, all 64 lanes active
#pragma unroll
        for (int j = 0; j < 16; j++) {
            float s = acc[j];
            float q = s * s;
#pragma unroll
            for (int m = 1; m < 64; m <<= 1) { s += __shfl_xor(s, m, 64); q += __shfl_xor(q, m, 64); }
            if (lane == 0) {
                atomicAdd(&rawOut[c0 + j], s);
                atomicAdd(&rawOut[64 + c0 + j], q);
            }
        }
    }
}

// concat GEMM: C = [act(B0)|act(B1)|act(B2)|act(B3)] @ W[256 x 64] + bias, fused stats
__global__ __launch_bounds__(256) void k_gemm_out1_t(const float* __restrict__ B0, const float* __restrict__ B1,
                                                     const float* __restrict__ B2, const float* __restrict__ B3,
                                                     const float* __restrict__ R0, const float* __restrict__ R1,
                                                     const float* __restrict__ R2, const float* __restrict__ R3,
                                                     const float* __restrict__ G0, const float* __restrict__ G1,
                                                     const float* __restrict__ G2, const float* __restrict__ G3,
                                                     const float* __restrict__ E0, const float* __restrict__ E1,
                                                     const float* __restrict__ E2, const float* __restrict__ E3,
                                                     float invN,
                                                     const float* __restrict__ W, const float* __restrict__ bias,
                                                     float* __restrict__ C, float* __restrict__ rawOut, int n) {
    __shared__ float stl[4][2 * HID];
    {
        int p = threadIdx.x >> 6, c = threadIdx.x & 63;
        const float* rp[4] = {R0, R1, R2, R3};
        const float* gp[4] = {G0, G1, G2, G3};
        const float* ep[4] = {E0, E1, E2, E3};
        float s, t;
        bn_fin(rp[p], gp[p], ep[p], invN, c, s, t);
        stl[p][c] = s;
        stl[p][HID + c] = t;
        __syncthreads();
    }
    int w = threadIdx.x >> 6, lane = threadIdx.x & 63;
    int row = blockIdx.x * 64 + lane;
    int c0 = w * 16;
    bool valid = row < n;
    float acc[16];
#pragma unroll
    for (int j = 0; j < 16; j++) acc[j] = valid ? bias[c0 + j] : 0.f;
    if (valid) {
        const float* bufs[4] = {B0, B1, B2, B3};
#pragma unroll
        for (int pp = 0; pp < 4; pp++) {
            const float4* a4 = (const float4*)(bufs[pp] + (size_t)row * HID);
            const float* Wp = W + pp * HID * HID;
#pragma unroll 4
            for (int kk = 0; kk < HID / 4; kk++) {
                float4 av = a4[kk];
                float a[4] = {av.x, av.y, av.z, av.w};
#pragma unroll
                for (int u = 0; u < 4; u++) {
                    int k = kk * 4 + u;
                    float xv = relu_aff(a[u], stl[pp][k], stl[pp][HID + k]);
#pragma unroll
                    for (int j = 0; j < 16; j++) acc[j] = fmaf(xv, Wp[k * HID + c0 + j], acc[j]);
                }
            }
        }
        float4* cp = (float4*)(C + (size_t)row * HID + c0);
#pragma unroll
        for (int j = 0; j < 4; j++)
            cp[j] = make_float4(acc[4 * j], acc[4 * j + 1], acc[4 * j + 2], acc[4 * j + 3]);
    }
#pragma unroll
    for (int j = 0; j < 16; j++) {
        float s = acc[j];
        float q = s * s;
#pragma unroll
        for (int m = 1; m < 64; m <<= 1) { s += __shfl_xor(s, m, 64); q += __shfl_xor(q, m, 64); }
        if (lane == 0) {
            atomicAdd(&rawOut[c0 + j], s);
            atomicAdd(&rawOut[64 + c0 + j], q);
        }
    }
}

// final GEMM: C[n x 10] = act(A[n x 64]) @ W[64 x 10] + bias. K split across 4 waves,
// LDS partial reduce, wave 0 writes.
__global__ __launch_bounds__(256) void k_gemm_out2_t(const float* __restrict__ A,
                                                     const float* __restrict__ raw, const float* __restrict__ g,
                                                     const float* __restrict__ b, float invN,
                                                     const float* __restrict__ W, const float* __restrict__ bias,
                                                     float* __restrict__ C, int n) {
    __shared__ float stl[2 * HID];
    if (threadIdx.x < HID) {
        float s, t;
        bn_fin(raw, g, b, invN, threadIdx.x, s, t);
        stl[threadIdx.x] = s;
        stl[HID + threadIdx.x] = t;
    }
    __syncthreads();
    int w = threadIdx.x >> 6, lane = threadIdx.x & 63;
    int row = blockIdx.x * 64 + lane;
    bool valid = row < n;
    float acc[10];
#pragma unroll
    for (int j = 0; j < 10; j++) acc[j] = 0.f;
    if (valid) {
        const float4* a4 = (const float4*)(A + (size_t)row * HID) + w * 4;
#pragma unroll
        for (int kk = 0; kk < 4; kk++) {
            float4 av = a4[kk];
            float a[4] = {av.x, av.y, av.z, av.w};
#pragma unroll
            for (int u = 0; u < 4; u++) {
                int k = w * 16 + kk * 4 + u;
                float xv = relu_aff(a[u], stl[k], stl[HID + k]);
#pragma unroll
                for (int j = 0; j < 10; j++) acc[j] = fmaf(xv, W[k * 10 + j], acc[j]);
            }
        }
    }
    __shared__ float part[4][64][10];
#pragma unroll
    for (int j = 0; j < 10; j++) part[w][lane][j] = acc[j];
    __syncthreads();
    if (w == 0 && valid) {
        float* cp = C + (size_t)row * 10;
#pragma unroll
        for (int j = 0; j < 10; j++)
            cp[j] = bias[j] + part[0][lane][j] + part[1][lane][j] + part[2][lane][j] + part[3][lane][j];
    }
}

// in-place z = relu_aff(x, s2, t2) (affine from rawIn) + accumulate stats of z into rawOut
__global__ __launch_bounds__(256) void k_affine_stats(float* __restrict__ X,
                                                      const float* __restrict__ rawIn,
                                                      const float* __restrict__ g, const float* __restrict__ b,
                                                      float invN,
                                                      float* __restrict__ rawOut, long long n64) {
    long long stride = (long long)gridDim.x * 256;
    long long i0 = (long long)blockIdx.x * 256 + threadIdx.x;
    int col = threadIdx.x & 63;
    float sA, tA;
    bn_fin(rawIn, g, b, invN, col, sA, tA);
    float s = 0.f, q = 0.f;
    for (long long i = i0; i < n64; i += stride) {
        float v = relu_aff(X[i], sA, tA);
        X[i] = v;
        s += v; q = fmaf(v, v, q);
    }
    __shared__ float ls[256], lq[256];
    ls[threadIdx.x] = s; lq[threadIdx.x] = q;
    __syncthreads();
    if (threadIdx.x < 64) {
        s = ls[threadIdx.x] + ls[threadIdx.x + 64] + ls[threadIdx.x + 128] + ls[threadIdx.x + 192];
        q = lq[threadIdx.x] + lq[threadIdx.x + 64] + lq[threadIdx.x + 128] + lq[threadIdx.x + 192];
        atomicAdd(&rawOut[col], s);
        atomicAdd(&rawOut[64 + col], q);
    }
}

extern "C" void kernel_launch(void* const* d_in, const int* in_sizes, int n_in,
                              void* d_out, int out_size, void* d_ws, size_t ws_size,
                              hipStream_t stream) {
    const float* x = (const float*)d_in[0];
    const int* ei = (const int*)d_in[1];
    const float* W_in = (const float*)d_in[2];
    const float* b_in = (const float*)d_in[3];
    const float* g_in = (const float*)d_in[4];
    const float* be_in = (const float*)d_in[5];
    const float* epsp = (const float*)d_in[6];
    const float* W1 = (const float*)d_in[7];
    const float* b1 = (const float*)d_in[8];
    const float* g1 = (const float*)d_in[9];
    const float* be1 = (const float*)d_in[10];
    const float* W2 = (const float*)d_in[11];
    const float* b2 = (const float*)d_in[12];
    const float* g2 = (const float*)d_in[13];
    const float* be2 = (const float*)d_in[14];
    const float* g_post = (const float*)d_in[15];
    const float* be_post = (const float*)d_in[16];
    const float* W_out1 = (const float*)d_in[17];
    const float* b_out1 = (const float*)d_in[18];
    const float* g_out = (const float*)d_in[19];
    const float* be_out = (const float*)d_in[20];
    const float* W_out2 = (const float*)d_in[21];
    const float* b_out2 = (const float*)d_in[22];

    const int N = in_sizes[0] / HID;
    const int E = in_sizes[1] / 2;
    const int* srcp = ei;
    const int* dstp = ei + E;

    const int nbk = (N + (1 << BK_SHIFT) - 1) >> BK_SHIFT;
    if (nbk > BK_MAX) return;        // unsupported shape -> fail loudly
    if (N > (1 << 24)) return;       // src must fit 24 bits in packed pair

    size_t NODE = (size_t)N * HID;
    float* f = (float*)d_ws;
    float* pre0 = f;                 // stage-0 pre-BN (kept for concat)
    float* z0 = f + NODE;            // layer pre2 -> (in place) post-BN2-relu, kept for concat
    float* z1 = f + 2 * NODE;
    float* z2 = f + 3 * NODE;
    float* o = f + 4 * NODE;         // aggregation output (pairs overlay during CSR build)
    float* p = f + 5 * NODE;         // gemm1 output / head pre-BN (reused)
    int* rc = (int*)(f + 6 * NODE);  // row offsets, N+1
    int* col = rc + (N + 1);         // E
    int* gh = col + E;               // bucket hist, 512
    int* boff = gh + 512;            // bucket offsets, 513
    int* gcur = boff + 513;          // bucket cursors, 512
    float* raw = (float*)(gcur + 512);  // 11 stages x {sum[64], sumsq[64]}
    unsigned* pairs = (unsigned*)o;  // E packed (local_dst<<24 | src), overlays o

    size_t need = (size_t)(6 * NODE) * 4 + ((size_t)(N + 1) + E + 1537) * 4 + (size_t)11 * 128 * 4;
    if (ws_size < need) return;  // fail loudly (output stays poisoned)

    float invN = 1.0f / (float)N;
    int gt = (N + 63) / 64;          // tiled-GEMM grid
    int pb = (E + 256 * PART_EPT - 1) / (256 * PART_EPT);

    hipMemsetAsync(gh, 0, 512 * sizeof(int), stream);
    hipMemsetAsync(raw, 0, (size_t)11 * 128 * sizeof(float), stream);

    k_bhist<<<512, 256, 0, stream>>>(dstp, gh, E, nbk);
    k_bscan<<<1, 512, 0, stream>>>(gh, boff, gcur, nbk);
    k_bpart<<<pb, 256, 0, stream>>>(srcp, dstp, gcur, pairs, E);
    k_bucket_csr<<<nbk, 256, 0, stream>>>(pairs, boff, rc, col, N, E, nbk);

    // input projection (no input affine), stats of pre0 fused -> raw stage 0
    k_gemm_t64<false, true><<<gt, 256, 0, stream>>>(x, nullptr, nullptr, nullptr, invN,
                                                    W_in, b_in, pre0, raw, N);

    float* zb[3] = {z0, z1, z2};
    for (int i = 0; i < LAYERS; i++) {
        int s1 = 1 + 3 * i, s2 = 2 + 3 * i, sp = 3 + 3 * i;
        const float* hb = (i == 0) ? pre0 : zb[i - 1];
        const float* rh = (i == 0) ? raw : raw + (size_t)(3 * i) * 128;
        const float* gh2 = (i == 0) ? g_in : g_post + (i - 1) * HID;
        const float* eh = (i == 0) ? be_in : be_post + (i - 1) * HID;
        k_agg<<<(N + 3) / 4, 256, 0, stream>>>(hb, rh, gh2, eh, invN, rc, col, epsp, i, o, N);
        // gemm1: p = o @ W1 + b1, stats -> s1
        k_gemm_t64<false, true><<<gt, 256, 0, stream>>>(o, nullptr, nullptr, nullptr, invN,
                                                        W1 + (size_t)i * HID * HID, b1 + i * HID,
                                                        p, raw + (size_t)s1 * 128, N);
        // gemm2: z = act(p; s1,g1,be1) @ W2 + b2, stats -> s2
        k_gemm_t64<true, true><<<gt, 256, 0, stream>>>(p, raw + (size_t)s1 * 128, g1 + i * HID, be1 + i * HID,
                                                       invN, W2 + (size_t)i * HID * HID, b2 + i * HID,
                                                       zb[i], raw + (size_t)s2 * 128, N);
        // z <- relu_aff(z; s2,g2,be2) in place, stats of result -> sp
        k_affine_stats<<<512, 256, 0, stream>>>(zb[i], raw + (size_t)s2 * 128, g2 + i * HID, be2 + i * HID, invN,
                                                raw + (size_t)sp * 128, (long long)NODE);
    }

    // head: concat -> 256x64 GEMM (stats fused -> s10) -> BN -> relu -> 64x10 GEMM
    k_gemm_out1_t<<<gt, 256, 0, stream>>>(pre0, z0, z1, z2,
                                          raw, raw + 3 * 128, raw + 6 * 128, raw + 9 * 128,
                                          g_in, g_post, g_post + HID, g_post + 2 * HID,
                                          be_in, be_post, be_post + HID, be_post + 2 * HID,
                                          invN, W_out1, b_out1, p, raw + 10 * 128, N);
    k_gemm_out2_t<<<gt, 256, 0, stream>>>(p, raw + 10 * 128, g_out, be_out, invN,
                                          W_out2, b_out2, (float*)d_out, N);
}

// Round 5
// 5487.302 us; speedup vs baseline: 1.0475x; 1.0475x over previous
//
#include <hip/hip_runtime.h>

// GIN forward, MI355X. Round 5:
//  - Round 4 tiled GEMMs kept (64-row tile, 4 waves x 16-col slice, acc[16], fused
//    column stats) BUT wave-uniform column offset c0 forced into SGPR via
//    __builtin_amdgcn_readfirstlane. Round 4 regression root cause: c0 =
//    (threadIdx>>6)*16 is wave-uniform but LLVM divergence analysis can't prove it,
//    so W reads became 64-lane redundant vector loads (VALUBusy 19.8->4.3%,
//    741us/dispatch). readfirstlane restores scalar s_load broadcast of W.
//  - CSR build: bucketed partition + LDS-local scatter (Round 3).
//  - k_agg: hierarchical unroll (8/4/2/1).

#define HID 64
#define LAYERS 3
#define BN_EPS 1e-5f

#define BK_SHIFT 8          // 256 nodes per bucket
#define BK_MAX 512          // max buckets supported (N <= 131072)
#define PART_EPT 16         // edges per thread in k_bpart

__device__ __forceinline__ float relu_aff(float x, float s, float t) {
    return fmaxf(fmaf(x, s, t), 0.f);
}

// compute affine (s,t) for column c from raw sums
__device__ __forceinline__ void bn_fin(const float* __restrict__ raw, const float* __restrict__ g,
                                       const float* __restrict__ b, float invN, int c,
                                       float& s, float& t) {
    float m = raw[c] * invN;
    float v = fmaf(-m, m, raw[64 + c] * invN);
    float r = rsqrtf(v + BN_EPS);
    s = r * g[c];
    t = fmaf(-m, s, b[c]);
}

// ---------------- bucketed CSR build ----------------

__global__ __launch_bounds__(256) void k_bhist(const int* __restrict__ dst, int* __restrict__ gh,
                                               int E, int nbk) {
    __shared__ int h[BK_MAX];
    for (int i = threadIdx.x; i < BK_MAX; i += 256) h[i] = 0;
    __syncthreads();
    int stride = gridDim.x * 256;
    for (int e = blockIdx.x * 256 + threadIdx.x; e < E; e += stride)
        atomicAdd(&h[dst[e] >> BK_SHIFT], 1);
    __syncthreads();
    for (int i = threadIdx.x; i < nbk; i += 256)
        if (h[i]) atomicAdd(&gh[i], h[i]);
}

__global__ __launch_bounds__(512) void k_bscan(const int* __restrict__ gh, int* __restrict__ boff,
                                               int* __restrict__ gcur, int nbk) {
    int lane = threadIdx.x & 63, wid = threadIdx.x >> 6;
    int v = (threadIdx.x < nbk) ? gh[threadIdx.x] : 0;
    int incl = v;
    for (int d = 1; d < 64; d <<= 1) { int y = __shfl_up(incl, d); if (lane >= d) incl += y; }
    __shared__ int ws[8];
    if (lane == 63) ws[wid] = incl;
    __syncthreads();
    if (threadIdx.x == 0) { int a = 0; for (int w = 0; w < 8; w++) { int t = ws[w]; ws[w] = a; a += t; } }
    __syncthreads();
    int excl = incl - v + ws[wid];
    if (threadIdx.x < nbk) { boff[threadIdx.x] = excl; gcur[threadIdx.x] = excl; }
    if (threadIdx.x == nbk - 1) boff[nbk] = excl + v;
}

__global__ __launch_bounds__(256) void k_bpart(const int* __restrict__ src, const int* __restrict__ dst,
                                               int* __restrict__ gcur, unsigned* __restrict__ pairs,
                                               int E) {
    __shared__ int h[BK_MAX], cur[BK_MAX], base[BK_MAX];
    int e0 = blockIdx.x * (256 * PART_EPT);
    int eend = min(e0 + 256 * PART_EPT, E);
    for (int i = threadIdx.x; i < BK_MAX; i += 256) h[i] = 0;
    __syncthreads();
    for (int e = e0 + threadIdx.x; e < eend; e += 256)
        atomicAdd(&h[dst[e] >> BK_SHIFT], 1);
    __syncthreads();
    for (int i = threadIdx.x; i < BK_MAX; i += 256) {
        cur[i] = 0;
        base[i] = h[i] ? atomicAdd(&gcur[i], h[i]) : 0;
    }
    __syncthreads();
    for (int e = e0 + threadIdx.x; e < eend; e += 256) {
        int d = dst[e];
        int b = d >> BK_SHIFT;
        int r = atomicAdd(&cur[b], 1);
        pairs[base[b] + r] = ((unsigned)(d & ((1 << BK_SHIFT) - 1)) << 24) | (unsigned)src[e];
    }
}

__global__ __launch_bounds__(256) void k_bucket_csr(const unsigned* __restrict__ pairs,
                                                    const int* __restrict__ boff,
                                                    int* __restrict__ row_off, int* __restrict__ col,
                                                    int N, int E, int nbk) {
    int b = blockIdx.x;
    int p0 = boff[b], p1 = boff[b + 1];
    int base_node = b << BK_SHIFT;
    int nn = min(256, N - base_node);
    __shared__ int h[256], cur[256];
    h[threadIdx.x] = 0;
    __syncthreads();
    for (int p = p0 + threadIdx.x; p < p1; p += 256)
        atomicAdd(&h[pairs[p] >> 24], 1);
    __syncthreads();
    int v = h[threadIdx.x];
    int lane = threadIdx.x & 63, wid = threadIdx.x >> 6;
    int incl = v;
    for (int d = 1; d < 64; d <<= 1) { int y = __shfl_up(incl, d); if (lane >= d) incl += y; }
    __shared__ int ws[4];
    if (lane == 63) ws[wid] = incl;
    __syncthreads();
    if (threadIdx.x == 0) { int a = 0; for (int w = 0; w < 4; w++) { int t = ws[w]; ws[w] = a; a += t; } }
    __syncthreads();
    int excl = incl - v + ws[wid];
    if (threadIdx.x < nn) row_off[base_node + threadIdx.x] = p0 + excl;
    if (b == nbk - 1 && threadIdx.x == 0) row_off[N] = E;
    cur[threadIdx.x] = excl;
    __syncthreads();
    for (int p = p0 + threadIdx.x; p < p1; p += 256) {
        unsigned pk = pairs[p];
        int local = pk >> 24;
        int r = atomicAdd(&cur[local], 1);
        col[p0 + r] = (int)(pk & 0xFFFFFFu);
    }
}

// ---------------- aggregation: o = (1+eps)*act(h) + sum act(h[src]) ----------------
__global__ __launch_bounds__(256) void k_agg(const float* __restrict__ hb,
                                             const float* __restrict__ raw, const float* __restrict__ g,
                                             const float* __restrict__ b, float invN,
                                             const int* __restrict__ row_off, const int* __restrict__ col,
                                             const float* __restrict__ epsp, int li,
                                             float* __restrict__ o, int n) {
    int wid = threadIdx.x >> 6, lane = threadIdx.x & 63;
    int node = blockIdx.x * 4 + wid;
    if (node >= n) return;
    float s, t;
    bn_fin(raw, g, b, invN, lane, s, t);
    float ope = 1.f + epsp[li];
    float acc = ope * relu_aff(hb[(size_t)node * HID + lane], s, t);
    int e = row_off[node], b1 = row_off[node + 1];

    while (e + 8 <= b1) {
        int i0 = col[e], i1 = col[e + 1], i2 = col[e + 2], i3 = col[e + 3];
        int i4 = col[e + 4], i5 = col[e + 5], i6 = col[e + 6], i7 = col[e + 7];
        float v0 = hb[(size_t)i0 * HID + lane], v1 = hb[(size_t)i1 * HID + lane];
        float v2 = hb[(size_t)i2 * HID + lane], v3 = hb[(size_t)i3 * HID + lane];
        float v4 = hb[(size_t)i4 * HID + lane], v5 = hb[(size_t)i5 * HID + lane];
        float v6 = hb[(size_t)i6 * HID + lane], v7 = hb[(size_t)i7 * HID + lane];
        acc += relu_aff(v0, s, t) + relu_aff(v1, s, t) + relu_aff(v2, s, t) + relu_aff(v3, s, t);
        acc += relu_aff(v4, s, t) + relu_aff(v5, s, t) + relu_aff(v6, s, t) + relu_aff(v7, s, t);
        e += 8;
    }
    if (e + 4 <= b1) {
        int i0 = col[e], i1 = col[e + 1], i2 = col[e + 2], i3 = col[e + 3];
        float v0 = hb[(size_t)i0 * HID + lane], v1 = hb[(size_t)i1 * HID + lane];
        float v2 = hb[(size_t)i2 * HID + lane], v3 = hb[(size_t)i3 * HID + lane];
        acc += relu_aff(v0, s, t) + relu_aff(v1, s, t) + relu_aff(v2, s, t) + relu_aff(v3, s, t);
        e += 4;
    }
    if (e + 2 <= b1) {
        int i0 = col[e], i1 = col[e + 1];
        float v0 = hb[(size_t)i0 * HID + lane], v1 = hb[(size_t)i1 * HID + lane];
        acc += relu_aff(v0, s, t) + relu_aff(v1, s, t);
        e += 2;
    }
    if (e < b1) acc += relu_aff(hb[(size_t)col[e] * HID + lane], s, t);

    o[(size_t)node * HID + lane] = acc;
}

// ---------------- tiled GEMM: C[n x 64] = act(A[n x 64]) @ W[64 x 64] + bias ----------------
// block = 256 threads = 4 waves over a 64-row tile; wave w owns cols [16w, 16w+16).
// c0 is wave-uniform -> forced to SGPR via readfirstlane so W/bias reads are s_loads.
template <bool AFF, bool STATS>
__global__ __launch_bounds__(256) void k_gemm_t64(const float* __restrict__ A,
                                                  const float* __restrict__ raw, const float* __restrict__ g,
                                                  const float* __restrict__ b, float invN,
                                                  const float* __restrict__ W, const float* __restrict__ bias,
                                                  float* __restrict__ C, float* __restrict__ rawOut, int n) {
    __shared__ float stl[2 * HID];
    if (AFF) {
        if (threadIdx.x < HID) {
            float s, t;
            bn_fin(raw, g, b, invN, threadIdx.x, s, t);
            stl[threadIdx.x] = s;
            stl[HID + threadIdx.x] = t;
        }
        __syncthreads();
    }
    int lane = threadIdx.x & 63;
    int c0 = __builtin_amdgcn_readfirstlane((threadIdx.x >> 6) * 16);  // SGPR, wave-uniform
    int row = blockIdx.x * 64 + lane;
    bool valid = row < n;
    float acc[16];
#pragma unroll
    for (int j = 0; j < 16; j++) acc[j] = valid ? bias[c0 + j] : 0.f;
    if (valid) {
        const float4* a4 = (const float4*)(A + (size_t)row * HID);
#pragma unroll 4
        for (int kk = 0; kk < HID / 4; kk++) {
            float4 av = a4[kk];
            float a[4] = {av.x, av.y, av.z, av.w};
#pragma unroll
            for (int u = 0; u < 4; u++) {
                int k = kk * 4 + u;
                float xv = a[u];
                if (AFF) xv = relu_aff(xv, stl[k], stl[HID + k]);
#pragma unroll
                for (int j = 0; j < 16; j++) acc[j] = fmaf(xv, W[k * HID + c0 + j], acc[j]);
            }
        }
        float4* cp = (float4*)(C + (size_t)row * HID + c0);
#pragma unroll
        for (int j = 0; j < 4; j++)
            cp[j] = make_float4(acc[4 * j], acc[4 * j + 1], acc[4 * j + 2], acc[4 * j + 3]);
    }
    if (STATS) {
        // invalid lanes contribute acc==0; no early returns above, all 64 lanes active
#pragma unroll
        for (int j = 0; j < 16; j++) {
            float s = acc[j];
            float q = s * s;
#pragma unroll
            for (int m = 1; m < 64; m <<= 1) { s += __shfl_xor(s, m, 64); q += __shfl_xor(q, m, 64); }
            if (lane == 0) {
                atomicAdd(&rawOut[c0 + j], s);
                atomicAdd(&rawOut[64 + c0 + j], q);
            }
        }
    }
}

// concat GEMM: C = [act(B0)|act(B1)|act(B2)|act(B3)] @ W[256 x 64] + bias, fused stats
__global__ __launch_bounds__(256) void k_gemm_out1_t(const float* __restrict__ B0, const float* __restrict__ B1,
                                                     const float* __restrict__ B2, const float* __restrict__ B3,
                                                     const float* __restrict__ R0, const float* __restrict__ R1,
                                                     const float* __restrict__ R2, const float* __restrict__ R3,
                                                     const float* __restrict__ G0, const float* __restrict__ G1,
                                                     const float* __restrict__ G2, const float* __restrict__ G3,
                                                     const float* __restrict__ E0, const float* __restrict__ E1,
                                                     const float* __restrict__ E2, const float* __restrict__ E3,
                                                     float invN,
                                                     const float* __restrict__ W, const float* __restrict__ bias,
                                                     float* __restrict__ C, float* __restrict__ rawOut, int n) {
    __shared__ float stl[4][2 * HID];
    {
        int p = threadIdx.x >> 6, c = threadIdx.x & 63;
        const float* rp[4] = {R0, R1, R2, R3};
        const float* gp[4] = {G0, G1, G2, G3};
        const float* ep[4] = {E0, E1, E2, E3};
        float s, t;
        bn_fin(rp[p], gp[p], ep[p], invN, c, s, t);
        stl[p][c] = s;
        stl[p][HID + c] = t;
        __syncthreads();
    }
    int lane = threadIdx.x & 63;
    int wv = threadIdx.x >> 6;
    int c0 = __builtin_amdgcn_readfirstlane(wv * 16);  // SGPR, wave-uniform
    int row = blockIdx.x * 64 + lane;
    bool valid = row < n;
    float acc[16];
#pragma unroll
    for (int j = 0; j < 16; j++) acc[j] = valid ? bias[c0 + j] : 0.f;
    if (valid) {
        const float* bufs[4] = {B0, B1, B2, B3};
#pragma unroll
        for (int pp = 0; pp < 4; pp++) {
            const float4* a4 = (const float4*)(bufs[pp] + (size_t)row * HID);
            const float* Wp = W + pp * HID * HID;
#pragma unroll 4
            for (int kk = 0; kk < HID / 4; kk++) {
                float4 av = a4[kk];
                float a[4] = {av.x, av.y, av.z, av.w};
#pragma unroll
                for (int u = 0; u < 4; u++) {
                    int k = kk * 4 + u;
                    float xv = relu_aff(a[u], stl[pp][k], stl[pp][HID + k]);
#pragma unroll
                    for (int j = 0; j < 16; j++) acc[j] = fmaf(xv, Wp[k * HID + c0 + j], acc[j]);
                }
            }
        }
        float4* cp = (float4*)(C + (size_t)row * HID + c0);
#pragma unroll
        for (int j = 0; j < 4; j++)
            cp[j] = make_float4(acc[4 * j], acc[4 * j + 1], acc[4 * j + 2], acc[4 * j + 3]);
    }
#pragma unroll
    for (int j = 0; j < 16; j++) {
        float s = acc[j];
        float q = s * s;
#pragma unroll
        for (int m = 1; m < 64; m <<= 1) { s += __shfl_xor(s, m, 64); q += __shfl_xor(q, m, 64); }
        if (lane == 0) {
            atomicAdd(&rawOut[c0 + j], s);
            atomicAdd(&rawOut[64 + c0 + j], q);
        }
    }
}

// final GEMM: C[n x 10] = act(A[n x 64]) @ W[64 x 10] + bias. K split across 4 waves,
// LDS partial reduce, wave 0 writes. k0 forced to SGPR for scalar W loads.
__global__ __launch_bounds__(256) void k_gemm_out2_t(const float* __restrict__ A,
                                                     const float* __restrict__ raw, const float* __restrict__ g,
                                                     const float* __restrict__ b, float invN,
                                                     const float* __restrict__ W, const float* __restrict__ bias,
                                                     float* __restrict__ C, int n) {
    __shared__ float stl[2 * HID];
    if (threadIdx.x < HID) {
        float s, t;
        bn_fin(raw, g, b, invN, threadIdx.x, s, t);
        stl[threadIdx.x] = s;
        stl[HID + threadIdx.x] = t;
    }
    __syncthreads();
    int lane = threadIdx.x & 63;
    int wv = threadIdx.x >> 6;
    int k0 = __builtin_amdgcn_readfirstlane(wv * 16);  // SGPR, wave-uniform
    int row = blockIdx.x * 64 + lane;
    bool valid = row < n;
    float acc[10];
#pragma unroll
    for (int j = 0; j < 10; j++) acc[j] = 0.f;
    if (valid) {
        const float4* a4 = (const float4*)(A + (size_t)row * HID + k0);
#pragma unroll
        for (int kk = 0; kk < 4; kk++) {
            float4 av = a4[kk];
            float a[4] = {av.x, av.y, av.z, av.w};
#pragma unroll
            for (int u = 0; u < 4; u++) {
                int k = k0 + kk * 4 + u;
                float xv = relu_aff(a[u], stl[k], stl[HID + k]);
#pragma unroll
                for (int j = 0; j < 10; j++) acc[j] = fmaf(xv, W[k * 10 + j], acc[j]);
            }
        }
    }
    __shared__ float part[4][64][10];
#pragma unroll
    for (int j = 0; j < 10; j++) part[wv][lane][j] = acc[j];
    __syncthreads();
    if (wv == 0 && valid) {
        float* cp = C + (size_t)row * 10;
#pragma unroll
        for (int j = 0; j < 10; j++)
            cp[j] = bias[j] + part[0][lane][j] + part[1][lane][j] + part[2][lane][j] + part[3][lane][j];
    }
}

// in-place z = relu_aff(x, s2, t2) (affine from rawIn) + accumulate stats of z into rawOut
__global__ __launch_bounds__(256) void k_affine_stats(float* __restrict__ X,
                                                      const float* __restrict__ rawIn,
                                                      const float* __restrict__ g, const float* __restrict__ b,
                                                      float invN,
                                                      float* __restrict__ rawOut, long long n64) {
    long long stride = (long long)gridDim.x * 256;
    long long i0 = (long long)blockIdx.x * 256 + threadIdx.x;
    int col = threadIdx.x & 63;
    float sA, tA;
    bn_fin(rawIn, g, b, invN, col, sA, tA);
    float s = 0.f, q = 0.f;
    for (long long i = i0; i < n64; i += stride) {
        float v = relu_aff(X[i], sA, tA);
        X[i] = v;
        s += v; q = fmaf(v, v, q);
    }
    __shared__ float ls[256], lq[256];
    ls[threadIdx.x] = s; lq[threadIdx.x] = q;
    __syncthreads();
    if (threadIdx.x < 64) {
        s = ls[threadIdx.x] + ls[threadIdx.x + 64] + ls[threadIdx.x + 128] + ls[threadIdx.x + 192];
        q = lq[threadIdx.x] + lq[threadIdx.x + 64] + lq[threadIdx.x + 128] + lq[threadIdx.x + 192];
        atomicAdd(&rawOut[col], s);
        atomicAdd(&rawOut[64 + col], q);
    }
}

extern "C" void kernel_launch(void* const* d_in, const int* in_sizes, int n_in,
                              void* d_out, int out_size, void* d_ws, size_t ws_size,
                              hipStream_t stream) {
    const float* x = (const float*)d_in[0];
    const int* ei = (const int*)d_in[1];
    const float* W_in = (const float*)d_in[2];
    const float* b_in = (const float*)d_in[3];
    const float* g_in = (const float*)d_in[4];
    const float* be_in = (const float*)d_in[5];
    const float* epsp = (const float*)d_in[6];
    const float* W1 = (const float*)d_in[7];
    const float* b1 = (const float*)d_in[8];
    const float* g1 = (const float*)d_in[9];
    const float* be1 = (const float*)d_in[10];
    const float* W2 = (const float*)d_in[11];
    const float* b2 = (const float*)d_in[12];
    const float* g2 = (const float*)d_in[13];
    const float* be2 = (const float*)d_in[14];
    const float* g_post = (const float*)d_in[15];
    const float* be_post = (const float*)d_in[16];
    const float* W_out1 = (const float*)d_in[17];
    const float* b_out1 = (const float*)d_in[18];
    const float* g_out = (const float*)d_in[19];
    const float* be_out = (const float*)d_in[20];
    const float* W_out2 = (const float*)d_in[21];
    const float* b_out2 = (const float*)d_in[22];

    const int N = in_sizes[0] / HID;
    const int E = in_sizes[1] / 2;
    const int* srcp = ei;
    const int* dstp = ei + E;

    const int nbk = (N + (1 << BK_SHIFT) - 1) >> BK_SHIFT;
    if (nbk > BK_MAX) return;        // unsupported shape -> fail loudly
    if (N > (1 << 24)) return;       // src must fit 24 bits in packed pair

    size_t NODE = (size_t)N * HID;
    float* f = (float*)d_ws;
    float* pre0 = f;                 // stage-0 pre-BN (kept for concat)
    float* z0 = f + NODE;            // layer pre2 -> (in place) post-BN2-relu, kept for concat
    float* z1 = f + 2 * NODE;
    float* z2 = f + 3 * NODE;
    float* o = f + 4 * NODE;         // aggregation output (pairs overlay during CSR build)
    float* p = f + 5 * NODE;         // gemm1 output / head pre-BN (reused)
    int* rc = (int*)(f + 6 * NODE);  // row offsets, N+1
    int* col = rc + (N + 1);         // E
    int* gh = col + E;               // bucket hist, 512
    int* boff = gh + 512;            // bucket offsets, 513
    int* gcur = boff + 513;          // bucket cursors, 512
    float* raw = (float*)(gcur + 512);  // 11 stages x {sum[64], sumsq[64]}
    unsigned* pairs = (unsigned*)o;  // E packed (local_dst<<24 | src), overlays o

    size_t need = (size_t)(6 * NODE) * 4 + ((size_t)(N + 1) + E + 1537) * 4 + (size_t)11 * 128 * 4;
    if (ws_size < need) return;  // fail loudly (output stays poisoned)

    float invN = 1.0f / (float)N;
    int gt = (N + 63) / 64;          // tiled-GEMM grid
    int pb = (E + 256 * PART_EPT - 1) / (256 * PART_EPT);

    hipMemsetAsync(gh, 0, 512 * sizeof(int), stream);
    hipMemsetAsync(raw, 0, (size_t)11 * 128 * sizeof(float), stream);

    k_bhist<<<512, 256, 0, stream>>>(dstp, gh, E, nbk);
    k_bscan<<<1, 512, 0, stream>>>(gh, boff, gcur, nbk);
    k_bpart<<<pb, 256, 0, stream>>>(srcp, dstp, gcur, pairs, E);
    k_bucket_csr<<<nbk, 256, 0, stream>>>(pairs, boff, rc, col, N, E, nbk);

    // input projection (no input affine), stats of pre0 fused -> raw stage 0
    k_gemm_t64<false, true><<<gt, 256, 0, stream>>>(x, nullptr, nullptr, nullptr, invN,
                                                    W_in, b_in, pre0, raw, N);

    float* zb[3] = {z0, z1, z2};
    for (int i = 0; i < LAYERS; i++) {
        int s1 = 1 + 3 * i, s2 = 2 + 3 * i, sp = 3 + 3 * i;
        const float* hb = (i == 0) ? pre0 : zb[i - 1];
        const float* rh = (i == 0) ? raw : raw + (size_t)(3 * i) * 128;
        const float* gh2 = (i == 0) ? g_in : g_post + (i - 1) * HID;
        const float* eh = (i == 0) ? be_in : be_post + (i - 1) * HID;
        k_agg<<<(N + 3) / 4, 256, 0, stream>>>(hb, rh, gh2, eh, invN, rc, col, epsp, i, o, N);
        // gemm1: p = o @ W1 + b1, stats -> s1
        k_gemm_t64<false, true><<<gt, 256, 0, stream>>>(o, nullptr, nullptr, nullptr, invN,
                                                        W1 + (size_t)i * HID * HID, b1 + i * HID,
                                                        p, raw + (size_t)s1 * 128, N);
        // gemm2: z = act(p; s1,g1,be1) @ W2 + b2, stats -> s2
        k_gemm_t64<true, true><<<gt, 256, 0, stream>>>(p, raw + (size_t)s1 * 128, g1 + i * HID, be1 + i * HID,
                                                       invN, W2 + (size_t)i * HID * HID, b2 + i * HID,
                                                       zb[i], raw + (size_t)s2 * 128, N);
        // z <- relu_aff(z; s2,g2,be2) in place, stats of result -> sp
        k_affine_stats<<<512, 256, 0, stream>>>(zb[i], raw + (size_t)s2 * 128, g2 + i * HID, be2 + i * HID, invN,
                                                raw + (size_t)sp * 128, (long long)NODE);
    }

    // head: concat -> 256x64 GEMM (stats fused -> s10) -> BN -> relu -> 64x10 GEMM
    k_gemm_out1_t<<<gt, 256, 0, stream>>>(pre0, z0, z1, z2,
                                          raw, raw + 3 * 128, raw + 6 * 128, raw + 9 * 128,
                                          g_in, g_post, g_post + HID, g_post + 2 * HID,
                                          be_in, be_post, be_post + HID, be_post + 2 * HID,
                                          invN, W_out1, b_out1, p, raw + 10 * 128, N);
    k_gemm_out2_t<<<gt, 256, 0, stream>>>(p, raw + 10 * 128, g_out, be_out, invN,
                                          W_out2, b_out2, (float*)d_out, N);
}

// Round 6
// 786.713 us; speedup vs baseline: 7.3065x; 6.9750x over previous
//
#include <hip/hip_runtime.h>

// GIN forward, MI355X. Round 6:
//  - ROOT CAUSE of R4/R5 collapse: fused column-stats used fp32 global atomicAdd.
//    Without -munsafe-fp-atomics HIP emits a global_atomic_cmpswap RETRY LOOP; with
//    1563 blocks x 32 atomics all hitting the SAME 128 floats, CAS retries serialize
//    catastrophically (evidence: WRITE_SIZE 31.3MB vs 25.6MB C output = +5.7MB ~
//    200K x 32B atomic write traffic; all pipes idle; readfirstlane scalarization
//    changed nothing).
//  - FIX: zero fp32 global atomics. Blocks store per-block stat partials (coalesced,
//    wave-reduced) into free workspace; k_redstats (128 waves) reduces partials->raw.
//  - Tiled GEMMs kept: 64-row tile, 4 waves x 16-col slice, acc[16], readfirstlane c0.
//  - CSR build: bucketed partition + LDS-local scatter (int atomics only - native).
//  - k_agg: hierarchical unroll (8/4/2/1).

#define HID 64
#define LAYERS 3
#define BN_EPS 1e-5f

#define BK_SHIFT 8          // 256 nodes per bucket
#define BK_MAX 512          // max buckets supported (N <= 131072)
#define PART_EPT 16         // edges per thread in k_bpart

__device__ __forceinline__ float relu_aff(float x, float s, float t) {
    return fmaxf(fmaf(x, s, t), 0.f);
}

// compute affine (s,t) for column c from raw sums
__device__ __forceinline__ void bn_fin(const float* __restrict__ raw, const float* __restrict__ g,
                                       const float* __restrict__ b, float invN, int c,
                                       float& s, float& t) {
    float m = raw[c] * invN;
    float v = fmaf(-m, m, raw[64 + c] * invN);
    float r = rsqrtf(v + BN_EPS);
    s = r * g[c];
    t = fmaf(-m, s, b[c]);
}

// ---------------- bucketed CSR build ----------------

__global__ __launch_bounds__(256) void k_bhist(const int* __restrict__ dst, int* __restrict__ gh,
                                               int E, int nbk) {
    __shared__ int h[BK_MAX];
    for (int i = threadIdx.x; i < BK_MAX; i += 256) h[i] = 0;
    __syncthreads();
    int stride = gridDim.x * 256;
    for (int e = blockIdx.x * 256 + threadIdx.x; e < E; e += stride)
        atomicAdd(&h[dst[e] >> BK_SHIFT], 1);
    __syncthreads();
    for (int i = threadIdx.x; i < nbk; i += 256)
        if (h[i]) atomicAdd(&gh[i], h[i]);
}

__global__ __launch_bounds__(512) void k_bscan(const int* __restrict__ gh, int* __restrict__ boff,
                                               int* __restrict__ gcur, int nbk) {
    int lane = threadIdx.x & 63, wid = threadIdx.x >> 6;
    int v = (threadIdx.x < nbk) ? gh[threadIdx.x] : 0;
    int incl = v;
    for (int d = 1; d < 64; d <<= 1) { int y = __shfl_up(incl, d); if (lane >= d) incl += y; }
    __shared__ int ws[8];
    if (lane == 63) ws[wid] = incl;
    __syncthreads();
    if (threadIdx.x == 0) { int a = 0; for (int w = 0; w < 8; w++) { int t = ws[w]; ws[w] = a; a += t; } }
    __syncthreads();
    int excl = incl - v + ws[wid];
    if (threadIdx.x < nbk) { boff[threadIdx.x] = excl; gcur[threadIdx.x] = excl; }
    if (threadIdx.x == nbk - 1) boff[nbk] = excl + v;
}

__global__ __launch_bounds__(256) void k_bpart(const int* __restrict__ src, const int* __restrict__ dst,
                                               int* __restrict__ gcur, unsigned* __restrict__ pairs,
                                               int E) {
    __shared__ int h[BK_MAX], cur[BK_MAX], base[BK_MAX];
    int e0 = blockIdx.x * (256 * PART_EPT);
    int eend = min(e0 + 256 * PART_EPT, E);
    for (int i = threadIdx.x; i < BK_MAX; i += 256) h[i] = 0;
    __syncthreads();
    for (int e = e0 + threadIdx.x; e < eend; e += 256)
        atomicAdd(&h[dst[e] >> BK_SHIFT], 1);
    __syncthreads();
    for (int i = threadIdx.x; i < BK_MAX; i += 256) {
        cur[i] = 0;
        base[i] = h[i] ? atomicAdd(&gcur[i], h[i]) : 0;
    }
    __syncthreads();
    for (int e = e0 + threadIdx.x; e < eend; e += 256) {
        int d = dst[e];
        int b = d >> BK_SHIFT;
        int r = atomicAdd(&cur[b], 1);
        pairs[base[b] + r] = ((unsigned)(d & ((1 << BK_SHIFT) - 1)) << 24) | (unsigned)src[e];
    }
}

__global__ __launch_bounds__(256) void k_bucket_csr(const unsigned* __restrict__ pairs,
                                                    const int* __restrict__ boff,
                                                    int* __restrict__ row_off, int* __restrict__ col,
                                                    int N, int E, int nbk) {
    int b = blockIdx.x;
    int p0 = boff[b], p1 = boff[b + 1];
    int base_node = b << BK_SHIFT;
    int nn = min(256, N - base_node);
    __shared__ int h[256], cur[256];
    h[threadIdx.x] = 0;
    __syncthreads();
    for (int p = p0 + threadIdx.x; p < p1; p += 256)
        atomicAdd(&h[pairs[p] >> 24], 1);
    __syncthreads();
    int v = h[threadIdx.x];
    int lane = threadIdx.x & 63, wid = threadIdx.x >> 6;
    int incl = v;
    for (int d = 1; d < 64; d <<= 1) { int y = __shfl_up(incl, d); if (lane >= d) incl += y; }
    __shared__ int ws[4];
    if (lane == 63) ws[wid] = incl;
    __syncthreads();
    if (threadIdx.x == 0) { int a = 0; for (int w = 0; w < 4; w++) { int t = ws[w]; ws[w] = a; a += t; } }
    __syncthreads();
    int excl = incl - v + ws[wid];
    if (threadIdx.x < nn) row_off[base_node + threadIdx.x] = p0 + excl;
    if (b == nbk - 1 && threadIdx.x == 0) row_off[N] = E;
    cur[threadIdx.x] = excl;
    __syncthreads();
    for (int p = p0 + threadIdx.x; p < p1; p += 256) {
        unsigned pk = pairs[p];
        int local = pk >> 24;
        int r = atomicAdd(&cur[local], 1);
        col[p0 + r] = (int)(pk & 0xFFFFFFu);
    }
}

// ---------------- partial-stats reduce: raw[slot] = sum_b pst[b*128 + slot] ----------------
// 128 slots ({sum[64], sumsq[64]}), one wave per slot. grid = 32 blocks x 256 threads.
__global__ __launch_bounds__(256) void k_redstats(const float* __restrict__ pst,
                                                  float* __restrict__ rawOut, int nblk) {
    int slot = blockIdx.x * 4 + (threadIdx.x >> 6);  // 0..127
    int lane = threadIdx.x & 63;
    float s = 0.f;
    for (int b = lane; b < nblk; b += 64) s += pst[(size_t)b * 128 + slot];
#pragma unroll
    for (int m = 1; m < 64; m <<= 1) s += __shfl_xor(s, m, 64);
    if (lane == 0) rawOut[slot] = s;
}

// ---------------- aggregation: o = (1+eps)*act(h) + sum act(h[src]) ----------------
__global__ __launch_bounds__(256) void k_agg(const float* __restrict__ hb,
                                             const float* __restrict__ raw, const float* __restrict__ g,
                                             const float* __restrict__ b, float invN,
                                             const int* __restrict__ row_off, const int* __restrict__ col,
                                             const float* __restrict__ epsp, int li,
                                             float* __restrict__ o, int n) {
    int wid = threadIdx.x >> 6, lane = threadIdx.x & 63;
    int node = blockIdx.x * 4 + wid;
    if (node >= n) return;
    float s, t;
    bn_fin(raw, g, b, invN, lane, s, t);
    float ope = 1.f + epsp[li];
    float acc = ope * relu_aff(hb[(size_t)node * HID + lane], s, t);
    int e = row_off[node], b1 = row_off[node + 1];

    while (e + 8 <= b1) {
        int i0 = col[e], i1 = col[e + 1], i2 = col[e + 2], i3 = col[e + 3];
        int i4 = col[e + 4], i5 = col[e + 5], i6 = col[e + 6], i7 = col[e + 7];
        float v0 = hb[(size_t)i0 * HID + lane], v1 = hb[(size_t)i1 * HID + lane];
        float v2 = hb[(size_t)i2 * HID + lane], v3 = hb[(size_t)i3 * HID + lane];
        float v4 = hb[(size_t)i4 * HID + lane], v5 = hb[(size_t)i5 * HID + lane];
        float v6 = hb[(size_t)i6 * HID + lane], v7 = hb[(size_t)i7 * HID + lane];
        acc += relu_aff(v0, s, t) + relu_aff(v1, s, t) + relu_aff(v2, s, t) + relu_aff(v3, s, t);
        acc += relu_aff(v4, s, t) + relu_aff(v5, s, t) + relu_aff(v6, s, t) + relu_aff(v7, s, t);
        e += 8;
    }
    if (e + 4 <= b1) {
        int i0 = col[e], i1 = col[e + 1], i2 = col[e + 2], i3 = col[e + 3];
        float v0 = hb[(size_t)i0 * HID + lane], v1 = hb[(size_t)i1 * HID + lane];
        float v2 = hb[(size_t)i2 * HID + lane], v3 = hb[(size_t)i3 * HID + lane];
        acc += relu_aff(v0, s, t) + relu_aff(v1, s, t) + relu_aff(v2, s, t) + relu_aff(v3, s, t);
        e += 4;
    }
    if (e + 2 <= b1) {
        int i0 = col[e], i1 = col[e + 1];
        float v0 = hb[(size_t)i0 * HID + lane], v1 = hb[(size_t)i1 * HID + lane];
        acc += relu_aff(v0, s, t) + relu_aff(v1, s, t);
        e += 2;
    }
    if (e < b1) acc += relu_aff(hb[(size_t)col[e] * HID + lane], s, t);

    o[(size_t)node * HID + lane] = acc;
}

// ---------------- tiled GEMM: C[n x 64] = act(A[n x 64]) @ W[64 x 64] + bias ----------------
// block = 256 threads = 4 waves over a 64-row tile; wave w owns cols [16w, 16w+16).
// STATS: per-block column sum/sumsq partials -> pst[block*128 + {0..63 sum, 64..127 sq}],
// plain coalesced stores (NO fp32 global atomics).
template <bool AFF, bool STATS>
__global__ __launch_bounds__(256) void k_gemm_t64(const float* __restrict__ A,
                                                  const float* __restrict__ raw, const float* __restrict__ g,
                                                  const float* __restrict__ b, float invN,
                                                  const float* __restrict__ W, const float* __restrict__ bias,
                                                  float* __restrict__ C, float* __restrict__ pst, int n) {
    __shared__ float stl[2 * HID];
    if (AFF) {
        if (threadIdx.x < HID) {
            float s, t;
            bn_fin(raw, g, b, invN, threadIdx.x, s, t);
            stl[threadIdx.x] = s;
            stl[HID + threadIdx.x] = t;
        }
        __syncthreads();
    }
    int lane = threadIdx.x & 63;
    int c0 = __builtin_amdgcn_readfirstlane((threadIdx.x >> 6) * 16);  // SGPR, wave-uniform
    int row = blockIdx.x * 64 + lane;
    bool valid = row < n;
    float acc[16];
#pragma unroll
    for (int j = 0; j < 16; j++) acc[j] = valid ? bias[c0 + j] : 0.f;
    if (valid) {
        const float4* a4 = (const float4*)(A + (size_t)row * HID);
#pragma unroll 4
        for (int kk = 0; kk < HID / 4; kk++) {
            float4 av = a4[kk];
            float a[4] = {av.x, av.y, av.z, av.w};
#pragma unroll
            for (int u = 0; u < 4; u++) {
                int k = kk * 4 + u;
                float xv = a[u];
                if (AFF) xv = relu_aff(xv, stl[k], stl[HID + k]);
#pragma unroll
                for (int j = 0; j < 16; j++) acc[j] = fmaf(xv, W[k * HID + c0 + j], acc[j]);
            }
        }
        float4* cp = (float4*)(C + (size_t)row * HID + c0);
#pragma unroll
        for (int j = 0; j < 4; j++)
            cp[j] = make_float4(acc[4 * j], acc[4 * j + 1], acc[4 * j + 2], acc[4 * j + 3]);
    }
    if (STATS) {
        // invalid lanes contribute acc==0; all 64 lanes active here (no early return)
        float mysum = 0.f, mysq = 0.f;
#pragma unroll
        for (int j = 0; j < 16; j++) {
            float s = acc[j];
            float q = s * s;
#pragma unroll
            for (int m = 1; m < 64; m <<= 1) { s += __shfl_xor(s, m, 64); q += __shfl_xor(q, m, 64); }
            if (lane == j) { mysum = s; mysq = q; }
        }
        if (lane < 16) {
            pst[(size_t)blockIdx.x * 128 + c0 + lane] = mysum;
            pst[(size_t)blockIdx.x * 128 + 64 + c0 + lane] = mysq;
        }
    }
}

// concat GEMM: C = [act(B0)|act(B1)|act(B2)|act(B3)] @ W[256 x 64] + bias, partial stats
__global__ __launch_bounds__(256) void k_gemm_out1_t(const float* __restrict__ B0, const float* __restrict__ B1,
                                                     const float* __restrict__ B2, const float* __restrict__ B3,
                                                     const float* __restrict__ R0, const float* __restrict__ R1,
                                                     const float* __restrict__ R2, const float* __restrict__ R3,
                                                     const float* __restrict__ G0, const float* __restrict__ G1,
                                                     const float* __restrict__ G2, const float* __restrict__ G3,
                                                     const float* __restrict__ E0, const float* __restrict__ E1,
                                                     const float* __restrict__ E2, const float* __restrict__ E3,
                                                     float invN,
                                                     const float* __restrict__ W, const float* __restrict__ bias,
                                                     float* __restrict__ C, float* __restrict__ pst, int n) {
    __shared__ float stl[4][2 * HID];
    {
        int p = threadIdx.x >> 6, c = threadIdx.x & 63;
        const float* rp[4] = {R0, R1, R2, R3};
        const float* gp[4] = {G0, G1, G2, G3};
        const float* ep[4] = {E0, E1, E2, E3};
        float s, t;
        bn_fin(rp[p], gp[p], ep[p], invN, c, s, t);
        stl[p][c] = s;
        stl[p][HID + c] = t;
        __syncthreads();
    }
    int lane = threadIdx.x & 63;
    int c0 = __builtin_amdgcn_readfirstlane((threadIdx.x >> 6) * 16);  // SGPR, wave-uniform
    int row = blockIdx.x * 64 + lane;
    bool valid = row < n;
    float acc[16];
#pragma unroll
    for (int j = 0; j < 16; j++) acc[j] = valid ? bias[c0 + j] : 0.f;
    if (valid) {
        const float* bufs[4] = {B0, B1, B2, B3};
#pragma unroll
        for (int pp = 0; pp < 4; pp++) {
            const float4* a4 = (const float4*)(bufs[pp] + (size_t)row * HID);
            const float* Wp = W + pp * HID * HID;
#pragma unroll 4
            for (int kk = 0; kk < HID / 4; kk++) {
                float4 av = a4[kk];
                float a[4] = {av.x, av.y, av.z, av.w};
#pragma unroll
                for (int u = 0; u < 4; u++) {
                    int k = kk * 4 + u;
                    float xv = relu_aff(a[u], stl[pp][k], stl[pp][HID + k]);
#pragma unroll
                    for (int j = 0; j < 16; j++) acc[j] = fmaf(xv, Wp[k * HID + c0 + j], acc[j]);
                }
            }
        }
        float4* cp = (float4*)(C + (size_t)row * HID + c0);
#pragma unroll
        for (int j = 0; j < 4; j++)
            cp[j] = make_float4(acc[4 * j], acc[4 * j + 1], acc[4 * j + 2], acc[4 * j + 3]);
    }
    float mysum = 0.f, mysq = 0.f;
#pragma unroll
    for (int j = 0; j < 16; j++) {
        float s = acc[j];
        float q = s * s;
#pragma unroll
        for (int m = 1; m < 64; m <<= 1) { s += __shfl_xor(s, m, 64); q += __shfl_xor(q, m, 64); }
        if (lane == j) { mysum = s; mysq = q; }
    }
    if (lane < 16) {
        pst[(size_t)blockIdx.x * 128 + c0 + lane] = mysum;
        pst[(size_t)blockIdx.x * 128 + 64 + c0 + lane] = mysq;
    }
}

// final GEMM: C[n x 10] = act(A[n x 64]) @ W[64 x 10] + bias. K split across 4 waves,
// LDS partial reduce, wave 0 writes.
__global__ __launch_bounds__(256) void k_gemm_out2_t(const float* __restrict__ A,
                                                     const float* __restrict__ raw, const float* __restrict__ g,
                                                     const float* __restrict__ b, float invN,
                                                     const float* __restrict__ W, const float* __restrict__ bias,
                                                     float* __restrict__ C, int n) {
    __shared__ float stl[2 * HID];
    if (threadIdx.x < HID) {
        float s, t;
        bn_fin(raw, g, b, invN, threadIdx.x, s, t);
        stl[threadIdx.x] = s;
        stl[HID + threadIdx.x] = t;
    }
    __syncthreads();
    int lane = threadIdx.x & 63;
    int wv = threadIdx.x >> 6;
    int k0 = __builtin_amdgcn_readfirstlane(wv * 16);  // SGPR, wave-uniform
    int row = blockIdx.x * 64 + lane;
    bool valid = row < n;
    float acc[10];
#pragma unroll
    for (int j = 0; j < 10; j++) acc[j] = 0.f;
    if (valid) {
        const float4* a4 = (const float4*)(A + (size_t)row * HID + k0);
#pragma unroll
        for (int kk = 0; kk < 4; kk++) {
            float4 av = a4[kk];
            float a[4] = {av.x, av.y, av.z, av.w};
#pragma unroll
            for (int u = 0; u < 4; u++) {
                int k = k0 + kk * 4 + u;
                float xv = relu_aff(a[u], stl[k], stl[HID + k]);
#pragma unroll
                for (int j = 0; j < 10; j++) acc[j] = fmaf(xv, W[k * 10 + j], acc[j]);
            }
        }
    }
    __shared__ float part[4][64][10];
#pragma unroll
    for (int j = 0; j < 10; j++) part[wv][lane][j] = acc[j];
    __syncthreads();
    if (wv == 0 && valid) {
        float* cp = C + (size_t)row * 10;
#pragma unroll
        for (int j = 0; j < 10; j++)
            cp[j] = bias[j] + part[0][lane][j] + part[1][lane][j] + part[2][lane][j] + part[3][lane][j];
    }
}

// in-place z = relu_aff(x, s2, t2) (affine from rawIn) + partial stats of z into pst
__global__ __launch_bounds__(256) void k_affine_stats(float* __restrict__ X,
                                                      const float* __restrict__ rawIn,
                                                      const float* __restrict__ g, const float* __restrict__ b,
                                                      float invN,
                                                      float* __restrict__ pst, long long n64) {
    long long stride = (long long)gridDim.x * 256;
    long long i0 = (long long)blockIdx.x * 256 + threadIdx.x;
    int col = threadIdx.x & 63;
    float sA, tA;
    bn_fin(rawIn, g, b, invN, col, sA, tA);
    float s = 0.f, q = 0.f;
    for (long long i = i0; i < n64; i += stride) {
        float v = relu_aff(X[i], sA, tA);
        X[i] = v;
        s += v; q = fmaf(v, v, q);
    }
    __shared__ float ls[256], lq[256];
    ls[threadIdx.x] = s; lq[threadIdx.x] = q;
    __syncthreads();
    if (threadIdx.x < 64) {
        s = ls[threadIdx.x] + ls[threadIdx.x + 64] + ls[threadIdx.x + 128] + ls[threadIdx.x + 192];
        q = lq[threadIdx.x] + lq[threadIdx.x + 64] + lq[threadIdx.x + 128] + lq[threadIdx.x + 192];
        pst[(size_t)blockIdx.x * 128 + col] = s;
        pst[(size_t)blockIdx.x * 128 + 64 + col] = q;
    }
}

extern "C" void kernel_launch(void* const* d_in, const int* in_sizes, int n_in,
                              void* d_out, int out_size, void* d_ws, size_t ws_size,
                              hipStream_t stream) {
    const float* x = (const float*)d_in[0];
    const int* ei = (const int*)d_in[1];
    const float* W_in = (const float*)d_in[2];
    const float* b_in = (const float*)d_in[3];
    const float* g_in = (const float*)d_in[4];
    const float* be_in = (const float*)d_in[5];
    const float* epsp = (const float*)d_in[6];
    const float* W1 = (const float*)d_in[7];
    const float* b1 = (const float*)d_in[8];
    const float* g1 = (const float*)d_in[9];
    const float* be1 = (const float*)d_in[10];
    const float* W2 = (const float*)d_in[11];
    const float* b2 = (const float*)d_in[12];
    const float* g2 = (const float*)d_in[13];
    const float* be2 = (const float*)d_in[14];
    const float* g_post = (const float*)d_in[15];
    const float* be_post = (const float*)d_in[16];
    const float* W_out1 = (const float*)d_in[17];
    const float* b_out1 = (const float*)d_in[18];
    const float* g_out = (const float*)d_in[19];
    const float* be_out = (const float*)d_in[20];
    const float* W_out2 = (const float*)d_in[21];
    const float* b_out2 = (const float*)d_in[22];

    const int N = in_sizes[0] / HID;
    const int E = in_sizes[1] / 2;
    const int* srcp = ei;
    const int* dstp = ei + E;

    const int nbk = (N + (1 << BK_SHIFT) - 1) >> BK_SHIFT;
    if (nbk > BK_MAX) return;        // unsupported shape -> fail loudly
    if (N > (1 << 24)) return;       // src must fit 24 bits in packed pair

    size_t NODE = (size_t)N * HID;
    float* f = (float*)d_ws;
    float* pre0 = f;                 // stage-0 pre-BN (kept for concat)
    float* z0 = f + NODE;            // layer pre2 -> (in place) post-BN2-relu, kept for concat
    float* z1 = f + 2 * NODE;
    float* z2 = f + 3 * NODE;
    float* o = f + 4 * NODE;         // aggregation output (pairs/partials overlay when free)
    float* p = f + 5 * NODE;         // gemm1 output / head pre-BN (reused)
    int* rc = (int*)(f + 6 * NODE);  // row offsets, N+1
    int* col = rc + (N + 1);         // E
    int* gh = col + E;               // bucket hist, 512
    int* boff = gh + 512;            // bucket offsets, 513
    int* gcur = boff + 513;          // bucket cursors, 512
    float* raw = (float*)(gcur + 512);  // 11 stages x {sum[64], sumsq[64]}
    unsigned* pairs = (unsigned*)o;  // E packed (local_dst<<24 | src), overlays o

    size_t need = (size_t)(6 * NODE) * 4 + ((size_t)(N + 1) + E + 1537) * 4 + (size_t)11 * 128 * 4;
    if (ws_size < need) return;  // fail loudly (output stays poisoned)

    float invN = 1.0f / (float)N;
    int gt = (N + 63) / 64;          // tiled-GEMM grid (1563 @ N=100000)
    int pb = (E + 256 * PART_EPT - 1) / (256 * PART_EPT);

    hipMemsetAsync(gh, 0, 512 * sizeof(int), stream);

    k_bhist<<<512, 256, 0, stream>>>(dstp, gh, E, nbk);
    k_bscan<<<1, 512, 0, stream>>>(gh, boff, gcur, nbk);
    k_bpart<<<pb, 256, 0, stream>>>(srcp, dstp, gcur, pairs, E);
    k_bucket_csr<<<nbk, 256, 0, stream>>>(pairs, boff, rc, col, N, E, nbk);

    // input projection; partials -> o (pairs already consumed), reduce -> raw stage 0
    k_gemm_t64<false, true><<<gt, 256, 0, stream>>>(x, nullptr, nullptr, nullptr, invN,
                                                    W_in, b_in, pre0, o, N);
    k_redstats<<<32, 256, 0, stream>>>(o, raw, gt);

    float* zb[3] = {z0, z1, z2};
    for (int i = 0; i < LAYERS; i++) {
        int s1 = 1 + 3 * i, s2 = 2 + 3 * i, sp = 3 + 3 * i;
        const float* hb = (i == 0) ? pre0 : zb[i - 1];
        const float* rh = (i == 0) ? raw : raw + (size_t)(3 * i) * 128;
        const float* gh2 = (i == 0) ? g_in : g_post + (i - 1) * HID;
        const float* eh = (i == 0) ? be_in : be_post + (i - 1) * HID;
        k_agg<<<(N + 3) / 4, 256, 0, stream>>>(hb, rh, gh2, eh, invN, rc, col, epsp, i, o, N);
        // gemm1: p = o @ W1 + b1; partials -> zb[i] (free: written only by gemm2 later)
        k_gemm_t64<false, true><<<gt, 256, 0, stream>>>(o, nullptr, nullptr, nullptr, invN,
                                                        W1 + (size_t)i * HID * HID, b1 + i * HID,
                                                        p, zb[i], N);
        k_redstats<<<32, 256, 0, stream>>>(zb[i], raw + (size_t)s1 * 128, gt);
        // gemm2: zb[i] = act(p; s1) @ W2 + b2; partials -> o (free: consumed by gemm1)
        k_gemm_t64<true, true><<<gt, 256, 0, stream>>>(p, raw + (size_t)s1 * 128, g1 + i * HID, be1 + i * HID,
                                                       invN, W2 + (size_t)i * HID * HID, b2 + i * HID,
                                                       zb[i], o, N);
        k_redstats<<<32, 256, 0, stream>>>(o, raw + (size_t)s2 * 128, gt);
        // zb[i] <- relu_aff(zb[i]; s2) in place; partials -> o
        k_affine_stats<<<512, 256, 0, stream>>>(zb[i], raw + (size_t)s2 * 128, g2 + i * HID, be2 + i * HID, invN,
                                                o, (long long)NODE);
        k_redstats<<<32, 256, 0, stream>>>(o, raw + (size_t)sp * 128, 512);
    }

    // head: concat -> 256x64 GEMM (partials -> o, reduce -> s10) -> BN -> relu -> 64x10 GEMM
    k_gemm_out1_t<<<gt, 256, 0, stream>>>(pre0, z0, z1, z2,
                                          raw, raw + 3 * 128, raw + 6 * 128, raw + 9 * 128,
                                          g_in, g_post, g_post + HID, g_post + 2 * HID,
                                          be_in, be_post, be_post + HID, be_post + 2 * HID,
                                          invN, W_out1, b_out1, p, o, N);
    k_redstats<<<32, 256, 0, stream>>>(o, raw + 10 * 128, gt);
    k_gemm_out2_t<<<gt, 256, 0, stream>>>(p, raw + 10 * 128, g_out, be_out, invN,
                                          W_out2, b_out2, (float*)d_out, N);
}